// Round 7
// baseline (179.101 us; speedup 1.0000x reference)
//
#include <hip/hip_runtime.h>
#include <hip/hip_bf16.h>
#include <cmath>

#define B_     8
#define C_     512
#define N_     1024
#define HEADS_ 8
#define HD_    64
#define INST_  64   // B_ * HEADS_

typedef short v8s  __attribute__((ext_vector_type(8)));
typedef float v16f __attribute__((ext_vector_type(16)));
typedef unsigned short ushort_t;
typedef unsigned int   uint_t;

__device__ inline unsigned short f2bf(float x) {
    unsigned u = __builtin_bit_cast(unsigned, x);
    unsigned r = u + 0x7fffu + ((u >> 16) & 1u);
    return (unsigned short)(r >> 16);
}
__device__ inline float bf2f(unsigned short h) {
    unsigned u = ((unsigned)h) << 16;
    return __builtin_bit_cast(float, u);
}
// packed f32x2 -> bf16x2 (v_cvt_pk_bf16_f32 on gfx950); low short = .x
__device__ inline uint_t pkbf(float a, float b) {
    __hip_bfloat162 p = __float22bfloat162_rn(make_float2(a, b));
    uint_t r;
    __builtin_memcpy(&r, &p, 4);
    return r;
}

// ---------------------------------------------------------------------------
// Kernel 0a: weight transpose+split. w[which][c][d] -> wth/wtl[which*512+d][c]
// ---------------------------------------------------------------------------
__global__ __launch_bounds__(256) void prep_w_kernel(
    const float* __restrict__ wq, const float* __restrict__ wk,
    const float* __restrict__ wv,
    uint_t* __restrict__ wth, uint_t* __restrict__ wtl)
{
    __shared__ uint_t LH[64 * 32];
    __shared__ uint_t LL[64 * 32];
    const int which = blockIdx.z;
    const float* __restrict__ src = (which == 0) ? wq : (which == 1) ? wk : wv;
    const int d0 = blockIdx.x * 64;
    const int c0 = blockIdx.y * 64;
    const int t  = threadIdx.x;

    #pragma unroll
    for (int rep = 0; rep < 2; ++rep) {
        int idx = rep * 256 + t;
        int cp  = idx >> 4;
        int dq  = idx & 15;
        float4 fa = *(const float4*)&src[(size_t)(c0 + 2 * cp) * 512 + d0 + dq * 4];
        float4 fb = *(const float4*)&src[(size_t)(c0 + 2 * cp + 1) * 512 + d0 + dq * 4];
        float aa[4] = {fa.x, fa.y, fa.z, fa.w};
        float bb[4] = {fb.x, fb.y, fb.z, fb.w};
        #pragma unroll
        for (int j = 0; j < 4; ++j) {
            int d_l = dq * 4 + j;
            unsigned short ha = f2bf(aa[j]), hb = f2bf(bb[j]);
            unsigned short la = f2bf(aa[j] - bf2f(ha));
            unsigned short lb = f2bf(bb[j] - bf2f(hb));
            LH[d_l * 32 + (cp ^ (d_l & 31))] = (uint_t)ha | ((uint_t)hb << 16);
            LL[d_l * 32 + (cp ^ (d_l & 31))] = (uint_t)la | ((uint_t)lb << 16);
        }
    }
    __syncthreads();

    const int d_l = t >> 2;
    const int wq4 = (t & 3) * 8;
    uint_t vh[8], vl[8];
    #pragma unroll
    for (int i = 0; i < 8; ++i) {
        vh[i] = LH[d_l * 32 + ((wq4 + i) ^ (d_l & 31))];
        vl[i] = LL[d_l * 32 + ((wq4 + i) ^ (d_l & 31))];
    }
    size_t base = ((size_t)which * 512 + d0 + d_l) * 256 + c0 / 2 + wq4;
    *(uint4*)&wth[base]     = *(uint4*)&vh[0];
    *(uint4*)&wth[base + 4] = *(uint4*)&vh[4];
    *(uint4*)&wtl[base]     = *(uint4*)&vl[0];
    *(uint4*)&wtl[base + 4] = *(uint4*)&vl[4];
}

// ---------------------------------------------------------------------------
// Kernel 0b: x transpose+split. x[b][c][n] -> xth/xtl[b*1024+n][c]
// ---------------------------------------------------------------------------
__global__ __launch_bounds__(256) void prep_x_kernel(
    const float* __restrict__ x,
    uint_t* __restrict__ xth, uint_t* __restrict__ xtl)
{
    __shared__ uint_t LH[64 * 32];
    __shared__ uint_t LL[64 * 32];
    const int b = blockIdx.z;
    const float* __restrict__ src = x + (size_t)b * C_ * N_;
    const int d0 = blockIdx.x * 64;           // n base
    const int c0 = blockIdx.y * 64;           // c base
    const int t  = threadIdx.x;

    #pragma unroll
    for (int rep = 0; rep < 2; ++rep) {
        int idx = rep * 256 + t;
        int cp  = idx >> 4;
        int dq  = idx & 15;
        float4 fa = *(const float4*)&src[(size_t)(c0 + 2 * cp) * 1024 + d0 + dq * 4];
        float4 fb = *(const float4*)&src[(size_t)(c0 + 2 * cp + 1) * 1024 + d0 + dq * 4];
        float aa[4] = {fa.x, fa.y, fa.z, fa.w};
        float bb[4] = {fb.x, fb.y, fb.z, fb.w};
        #pragma unroll
        for (int j = 0; j < 4; ++j) {
            int d_l = dq * 4 + j;
            unsigned short ha = f2bf(aa[j]), hb = f2bf(bb[j]);
            unsigned short la = f2bf(aa[j] - bf2f(ha));
            unsigned short lb = f2bf(bb[j] - bf2f(hb));
            LH[d_l * 32 + (cp ^ (d_l & 31))] = (uint_t)ha | ((uint_t)hb << 16);
            LL[d_l * 32 + (cp ^ (d_l & 31))] = (uint_t)la | ((uint_t)lb << 16);
        }
    }
    __syncthreads();

    const int d_l = t >> 2;
    const int wq4 = (t & 3) * 8;
    uint_t vh[8], vl[8];
    #pragma unroll
    for (int i = 0; i < 8; ++i) {
        vh[i] = LH[d_l * 32 + ((wq4 + i) ^ (d_l & 31))];
        vl[i] = LL[d_l * 32 + ((wq4 + i) ^ (d_l & 31))];
    }
    size_t base = ((size_t)b * 1024 + d0 + d_l) * 256 + c0 / 2 + wq4;
    *(uint4*)&xth[base]     = *(uint4*)&vh[0];
    *(uint4*)&xth[base + 4] = *(uint4*)&vh[4];
    *(uint4*)&xtl[base]     = *(uint4*)&vl[0];
    *(uint4*)&xtl[base + 4] = *(uint4*)&vl[4];
}

// ---------------------------------------------------------------------------
// Kernel 1: MFMA QKV projection — double-buffered LDS + register prefetch.
// One barrier per K-step; vmcnt wait covered by a full compute phase.
// ---------------------------------------------------------------------------
__global__ __launch_bounds__(256) void proj_kernel(
    const ushort_t* __restrict__ xth, const ushort_t* __restrict__ xtl,
    const ushort_t* __restrict__ wth, const ushort_t* __restrict__ wtl,
    const float* __restrict__ bq, const float* __restrict__ bk,
    const float* __restrict__ bv,
    ushort_t* __restrict__ qh, ushort_t* __restrict__ ql,
    ushort_t* __restrict__ kh, ushort_t* __restrict__ kl,
    ushort_t* __restrict__ vt)
{
    __shared__ ushort_t POOL[32768];                 // 64 KB: 2 x (As 16K, Bs 16K)

    const int tok0  = blockIdx.x * 128;
    const int b     = tok0 >> 10;
    const int ntb   = tok0 & 1023;
    const int by    = blockIdx.y;
    const int which = by >> 2;                       // 0=q,1=k,2=v
    const int nloc0 = (by & 3) * 128;

    const int t   = threadIdx.x;
    const int w   = t >> 6;
    const int l   = t & 63;
    const int l31 = l & 31;
    const int h5  = l >> 5;
    const int wm  = w & 1;
    const int wn  = w >> 1;

    const int g   = t & 7;
    const int r0  = t >> 3;
    const int swz = g ^ (r0 & 7);
    const bool act = (which < 2) || (g < 4);         // V: hi planes only

    const ushort_t* baseA = ((g < 4) ? xth : xtl)
        + (size_t)(tok0 + r0) * 512 + (g & 3) * 8;
    const ushort_t* baseB = ((g < 4) ? wth : wtl)
        + (size_t)(which * 512 + nloc0 + r0) * 512 + (g & 3) * 8;

    v8s pfa[4], pfb[4];

    auto load_tile = [&](int k0) {
        #pragma unroll
        for (int rep = 0; rep < 4; ++rep)
            if (act) {
                pfa[rep] = *(const v8s*)(baseA + rep * 16384 + k0);
                pfb[rep] = *(const v8s*)(baseB + rep * 16384 + k0);
            }
    };
    auto store_tile = [&](int buf) {
        ushort_t* As = POOL + buf * 16384;
        ushort_t* Bs = As + 8192;
        #pragma unroll
        for (int rep = 0; rep < 4; ++rep)
            if (act) {
                int so = ((rep * 32 + r0) * 8 + swz) * 8;
                *(v8s*)&As[so] = pfa[rep];
                *(v8s*)&Bs[so] = pfb[rep];
            }
    };

    v16f acc[2][2] = {{{}, {}}, {{}, {}}};

    load_tile(0);
    store_tile(0);
    load_tile(32);
    __syncthreads();

    for (int step = 0; step < 16; ++step) {
        const ushort_t* As = POOL + (step & 1) * 16384;
        const ushort_t* Bs = As + 8192;

        #pragma unroll
        for (int kc = 0; kc < 2; ++kc) {
            v8s ahf[2], alf[2], bhf[2], blf[2];
            #pragma unroll
            for (int ms = 0; ms < 2; ++ms) {
                int rm = wm * 64 + ms * 32 + l31;
                ahf[ms] = *(const v8s*)&As[(rm * 8 + ((kc * 2 + h5) ^ (rm & 7))) * 8];
                if (which < 2)
                    alf[ms] = *(const v8s*)&As[(rm * 8 + ((4 + kc * 2 + h5) ^ (rm & 7))) * 8];
            }
            #pragma unroll
            for (int ns = 0; ns < 2; ++ns) {
                int rn = wn * 64 + ns * 32 + l31;
                bhf[ns] = *(const v8s*)&Bs[(rn * 8 + ((kc * 2 + h5) ^ (rn & 7))) * 8];
                if (which < 2)
                    blf[ns] = *(const v8s*)&Bs[(rn * 8 + ((4 + kc * 2 + h5) ^ (rn & 7))) * 8];
            }
            #pragma unroll
            for (int ms = 0; ms < 2; ++ms)
                #pragma unroll
                for (int ns = 0; ns < 2; ++ns) {
                    acc[ms][ns] = __builtin_amdgcn_mfma_f32_32x32x16_bf16(
                        ahf[ms], bhf[ns], acc[ms][ns], 0, 0, 0);
                    if (which < 2) {
                        acc[ms][ns] = __builtin_amdgcn_mfma_f32_32x32x16_bf16(
                            alf[ms], bhf[ns], acc[ms][ns], 0, 0, 0);
                        acc[ms][ns] = __builtin_amdgcn_mfma_f32_32x32x16_bf16(
                            ahf[ms], blf[ns], acc[ms][ns], 0, 0, 0);
                    }
                }
        }

        if (step < 15) {
            store_tile((step + 1) & 1);   // vmcnt wait here, after full compute
            __syncthreads();
            if (step < 14) load_tile((step + 2) * 32);
        }
    }

    // ---- epilogue ----
    if (which < 2) {
        ushort_t* oh = (which == 0) ? qh : kh;
        ushort_t* ol = (which == 0) ? ql : kl;
        const float* bias = (which == 0) ? bq : bk;
        #pragma unroll
        for (int ns = 0; ns < 2; ++ns) {
            int d_local = nloc0 + wn * 64 + ns * 32 + l31;
            float bvv  = bias[d_local];
            int head   = d_local >> 6;
            int hd     = d_local & 63;
            size_t pb  = (size_t)(b * HEADS_ + head) * 65536 + hd;
            #pragma unroll
            for (int ms = 0; ms < 2; ++ms)
                #pragma unroll
                for (int r = 0; r < 16; ++r) {
                    int n = ntb + wm * 64 + ms * 32 + (r & 3) + 8 * (r >> 2) + 4 * h5;
                    float val = acc[ms][ns][r] + bvv;
                    unsigned short hbits = f2bf(val);
                    oh[pb + (size_t)n * 64] = hbits;
                    ol[pb + (size_t)n * 64] = f2bf(val - bf2f(hbits));
                }
        }
    } else {
        float bvv[2];
        #pragma unroll
        for (int ns = 0; ns < 2; ++ns)
            bvv[ns] = bv[nloc0 + wn * 64 + ns * 32 + l31];
        __syncthreads();
        uint_t* TW = (uint_t*)POOL + w * 2048;   // wave-private 8 KB
        #pragma unroll
        for (int ms = 0; ms < 2; ++ms)
            #pragma unroll
            for (int ns = 0; ns < 2; ++ns)
                #pragma unroll
                for (int r = 0; r < 16; r += 2) {
                    int tok_l = ms * 32 + (r & 3) + 8 * (r >> 2) + 4 * h5;  // even
                    int hd_l  = ns * 32 + l31;
                    TW[hd_l * 32 + ((tok_l >> 1) ^ (hd_l & 31))] =
                        pkbf(acc[ms][ns][r] + bvv[ns], acc[ms][ns][r + 1] + bvv[ns]);
                }
        __syncthreads();
        const int head = (nloc0 + wn * 64) >> 6;
        uint_t* vtu = (uint_t*)vt;
        size_t base = (size_t)(b * HEADS_ + head) * 32768 + (size_t)l * 512
                    + (ntb + wm * 64) / 2;
        #pragma unroll
        for (int c = 0; c < 8; ++c) {
            uint_t wd[4];
            #pragma unroll
            for (int kk = 0; kk < 4; ++kk) {
                int wsx = c * 4 + kk;
                int w3 = wsx & 7;
                int sw = (wsx & ~7) | (w3 & 1) | (((w3 >> 1) & 1) << 2)
                                   | (((w3 >> 2) & 1) << 1);
                wd[kk] = TW[l * 32 + (sw ^ (l & 31))];
            }
            *(uint4*)&vtu[base + c * 4] = *(uint4*)&wd[0];
        }
    }
}

// ---------------------------------------------------------------------------
// Kernel 2: MFMA flash attention, S^T form — double-buffered LDS + packed
// bf16 P-conversion.
// ---------------------------------------------------------------------------
__global__ __launch_bounds__(256) void attn_kernel(
    const ushort_t* __restrict__ qh, const ushort_t* __restrict__ ql,
    const ushort_t* __restrict__ kh, const ushort_t* __restrict__ kl,
    const ushort_t* __restrict__ vt, float* __restrict__ out)
{
    __shared__ ushort_t POOL[24576];   // 48 KB: 2 x (KH 8K, KL 8K, VT 8K bytes)
    __shared__ float    RS[128];

    const int inst  = blockIdx.x;
    const int chunk = blockIdx.y;
    const int t     = threadIdx.x;
    const int w     = t >> 6;
    const int l     = t & 63;
    const int l31   = l & 31;
    const int h5    = l >> 5;

    const ushort_t* Qh = qh + (size_t)inst * 65536;
    const ushort_t* Ql = ql + (size_t)inst * 65536;
    const ushort_t* Kh = kh + (size_t)inst * 65536;
    const ushort_t* Kl = kl + (size_t)inst * 65536;
    const ushort_t* Vt = vt + (size_t)inst * 65536;

    const int qbase = chunk * 128 + w * 32;

    v8s aqh[4], aql[4];
    #pragma unroll
    for (int ks = 0; ks < 4; ++ks) {
        size_t off = (size_t)(qbase + l31) * 64 + ks * 16 + h5 * 8;
        aqh[ks] = *(const v8s*)&Qh[off];
        aql[ks] = *(const v8s*)&Ql[off];
    }

    const int g   = t & 7;
    const int r0  = t >> 3;
    const int swz = g ^ (r0 & 7);
    const ushort_t* baseKh = Kh + (size_t)r0 * 64 + g * 8;
    const ushort_t* baseKl = Kl + (size_t)r0 * 64 + g * 8;
    const ushort_t* baseV  = Vt + (size_t)r0 * 1024 + g * 8;

    v8s pk[2], pl[2], pv[2];
    auto load_tile = [&](int kt) {
        #pragma unroll
        for (int rep = 0; rep < 2; ++rep) {
            pk[rep] = *(const v8s*)(baseKh + (size_t)kt * 4096 + rep * 2048);
            pl[rep] = *(const v8s*)(baseKl + (size_t)kt * 4096 + rep * 2048);
            pv[rep] = *(const v8s*)(baseV + (size_t)rep * 32768 + kt * 64);
        }
    };
    auto store_tile = [&](int buf) {
        ushort_t* KH = POOL + buf * 12288;
        ushort_t* KL = KH + 4096;
        ushort_t* VT = KL + 4096;
        #pragma unroll
        for (int rep = 0; rep < 2; ++rep) {
            int so = ((rep * 32 + r0) * 8 + swz) * 8;
            *(v8s*)&KH[so] = pk[rep];
            *(v8s*)&KL[so] = pl[rep];
            *(v8s*)&VT[so] = pv[rep];
        }
    };

    v16f O0 = {}, O1 = {};
    float rsumv = 0.f;

    load_tile(0);
    store_tile(0);
    load_tile(1);
    __syncthreads();

    for (int kt = 0; kt < 16; ++kt) {
        const ushort_t* KH = POOL + (kt & 1) * 12288;
        const ushort_t* KL = KH + 4096;
        const ushort_t* VT = KL + 4096;

        #pragma unroll
        for (int t2 = 0; t2 < 2; ++t2) {
            v16f s = {};
            int kvrow = t2 * 32 + l31;
            #pragma unroll
            for (int ks = 0; ks < 4; ++ks) {
                int so = (kvrow * 8 + ((ks * 2 + h5) ^ (kvrow & 7))) * 8;
                v8s khf = *(const v8s*)&KH[so];
                v8s klf = *(const v8s*)&KL[so];
                s = __builtin_amdgcn_mfma_f32_32x32x16_bf16(khf, aqh[ks], s, 0, 0, 0);
                s = __builtin_amdgcn_mfma_f32_32x32x16_bf16(khf, aql[ks], s, 0, 0, 0);
                s = __builtin_amdgcn_mfma_f32_32x32x16_bf16(klf, aqh[ks], s, 0, 0, 0);
            }
            float e0[8], e1[8];
            #pragma unroll
            for (int j = 0; j < 8; ++j) {
                e0[j] = __expf(s[j] - 64.0f);
                e1[j] = __expf(s[8 + j] - 64.0f);
                rsumv += e0[j] + e1[j];
            }
            uint4 u0, u1;
            u0.x = pkbf(e0[0], e0[1]); u0.y = pkbf(e0[2], e0[3]);
            u0.z = pkbf(e0[4], e0[5]); u0.w = pkbf(e0[6], e0[7]);
            u1.x = pkbf(e1[0], e1[1]); u1.y = pkbf(e1[2], e1[3]);
            u1.z = pkbf(e1[4], e1[5]); u1.w = pkbf(e1[6], e1[7]);
            v8s p0 = __builtin_bit_cast(v8s, u0);
            v8s p1 = __builtin_bit_cast(v8s, u1);

            #pragma unroll
            for (int hh = 0; hh < 2; ++hh) {
                int rv = hh * 32 + l31;
                int g0 = (4 * t2 + h5)     ^ (rv & 7);
                int g1 = (4 * t2 + 2 + h5) ^ (rv & 7);
                v8s bv0 = *(const v8s*)&VT[(rv * 8 + g0) * 8];
                v8s bv1 = *(const v8s*)&VT[(rv * 8 + g1) * 8];
                if (hh == 0) {
                    O0 = __builtin_amdgcn_mfma_f32_32x32x16_bf16(p0, bv0, O0, 0, 0, 0);
                    O0 = __builtin_amdgcn_mfma_f32_32x32x16_bf16(p1, bv1, O0, 0, 0, 0);
                } else {
                    O1 = __builtin_amdgcn_mfma_f32_32x32x16_bf16(p0, bv0, O1, 0, 0, 0);
                    O1 = __builtin_amdgcn_mfma_f32_32x32x16_bf16(p1, bv1, O1, 0, 0, 0);
                }
            }
        }

        if (kt < 15) {
            store_tile((kt + 1) & 1);     // vmcnt wait after compute
            __syncthreads();
            if (kt < 14) load_tile(kt + 2);
        }
    }

    float tot = rsumv + __shfl_xor(rsumv, 32, 64);
    if (h5 == 0) RS[w * 32 + l31] = 1.0f / tot;
    __syncthreads();
    float invr[16];
    #pragma unroll
    for (int r = 0; r < 16; ++r)
        invr[r] = RS[w * 32 + (r & 3) + 8 * (r >> 2) + 4 * h5];

    const int b    = inst >> 3;
    const int head = inst & 7;
    float* ob = out + (size_t)b * C_ * N_;
    #pragma unroll
    for (int hh = 0; hh < 2; ++hh) {
        const v16f& O = hh ? O1 : O0;
        int c = head * 64 + hh * 32 + l31;
        #pragma unroll
        for (int qd = 0; qd < 4; ++qd) {
            int n = qbase + 8 * qd + 4 * h5;
            float4 o4;
            o4.x = O[qd * 4 + 0] * invr[qd * 4 + 0];
            o4.y = O[qd * 4 + 1] * invr[qd * 4 + 1];
            o4.z = O[qd * 4 + 2] * invr[qd * 4 + 2];
            o4.w = O[qd * 4 + 3] * invr[qd * 4 + 3];
            *(float4*)&ob[(size_t)c * N_ + n] = o4;
        }
    }
}

// ---------------------------------------------------------------------------
extern "C" void kernel_launch(void* const* d_in, const int* in_sizes, int n_in,
                              void* d_out, int out_size, void* d_ws, size_t ws_size,
                              hipStream_t stream) {
    const float* x  = (const float*)d_in[0];
    const float* wq = (const float*)d_in[1];
    const float* bq = (const float*)d_in[2];
    const float* wk = (const float*)d_in[3];
    const float* bk = (const float*)d_in[4];
    const float* wv = (const float*)d_in[5];
    const float* bv = (const float*)d_in[6];
    float* out = (float*)d_out;

    char* ws = (char*)d_ws;                        // ~59 MiB used
    ushort_t* wth = (ushort_t*)(ws);
    ushort_t* wtl = (ushort_t*)(ws + 1572864);
    ushort_t* xth = (ushort_t*)(ws + 3145728);
    ushort_t* xtl = (ushort_t*)(ws + 11534336);
    ushort_t* qh  = (ushort_t*)(ws + 19922944);
    ushort_t* ql  = (ushort_t*)(ws + 28311552);
    ushort_t* kh  = (ushort_t*)(ws + 36700160);
    ushort_t* kl  = (ushort_t*)(ws + 45088768);
    ushort_t* vt  = (ushort_t*)(ws + 53477376);

    prep_w_kernel<<<dim3(8, 8, 3), 256, 0, stream>>>(wq, wk, wv,
                                                     (uint_t*)wth, (uint_t*)wtl);
    prep_x_kernel<<<dim3(16, 8, 8), 256, 0, stream>>>(x, (uint_t*)xth, (uint_t*)xtl);
    proj_kernel<<<dim3(64, 12), 256, 0, stream>>>(xth, xtl, wth, wtl,
                                                  bq, bk, bv, qh, ql, kh, kl, vt);
    attn_kernel<<<dim3(64, 8), 256, 0, stream>>>(qh, ql, kh, kl, vt, out);
}

// Round 8
// 140.753 us; speedup vs baseline: 1.2724x; 1.2724x over previous
//
#include <hip/hip_runtime.h>
#include <hip/hip_bf16.h>
#include <cmath>

#define B_     8
#define C_     512
#define N_     1024
#define HEADS_ 8
#define HD_    64
#define INST_  64   // B_ * HEADS_

typedef short     v8s __attribute__((ext_vector_type(8)));
typedef _Float16  v8h __attribute__((ext_vector_type(8)));
typedef float    v16f __attribute__((ext_vector_type(16)));
typedef unsigned short ushort_t;
typedef unsigned int   uint_t;

__device__ inline ushort_t f2h(float x) {
    _Float16 h = (_Float16)x;
    ushort_t r; __builtin_memcpy(&r, &h, 2); return r;
}
// packed f32x2 -> bf16x2 (v_cvt_pk_bf16_f32); low short = .x
__device__ inline uint_t pkbf(float a, float b) {
    __hip_bfloat162 p = __float22bfloat162_rn(make_float2(a, b));
    uint_t r; __builtin_memcpy(&r, &p, 4); return r;
}

// ---------------------------------------------------------------------------
// Kernel 0: unified transpose + fp16-convert prep.
//  z in [0,3): w[which][c][d] -> wt[which*512+d][c] fp16
//  z in [3,11): x[b][c][n]    -> xt[b*1024+n][c]    fp16
// ---------------------------------------------------------------------------
__global__ __launch_bounds__(256) void prep_kernel(
    const float* __restrict__ x,
    const float* __restrict__ wq, const float* __restrict__ wk,
    const float* __restrict__ wv,
    uint_t* __restrict__ wt, uint_t* __restrict__ xt)
{
    __shared__ uint_t LH[64 * 32];
    const int z = blockIdx.z;
    const float* src;
    int srcStride;
    size_t outRow0;
    uint_t* oh;
    if (z < 3) {
        if (blockIdx.x >= 8) return;          // weights: only 8 col-tiles
        src = (z == 0) ? wq : (z == 1) ? wk : wv;
        srcStride = 512;
        outRow0 = (size_t)z * 512 + blockIdx.x * 64;
        oh = wt;
    } else {
        int b = z - 3;
        src = x + (size_t)b * C_ * N_;
        srcStride = 1024;
        outRow0 = (size_t)b * 1024 + blockIdx.x * 64;
        oh = xt;
    }
    const int d0 = blockIdx.x * 64;
    const int c0 = blockIdx.y * 64;
    const int t  = threadIdx.x;

    #pragma unroll
    for (int rep = 0; rep < 2; ++rep) {
        int idx = rep * 256 + t;
        int cp  = idx >> 4;          // c-pair
        int dq  = idx & 15;          // d-quad
        float4 fa = *(const float4*)&src[(size_t)(c0 + 2 * cp) * srcStride + d0 + dq * 4];
        float4 fb = *(const float4*)&src[(size_t)(c0 + 2 * cp + 1) * srcStride + d0 + dq * 4];
        float aa[4] = {fa.x, fa.y, fa.z, fa.w};
        float bb[4] = {fb.x, fb.y, fb.z, fb.w};
        #pragma unroll
        for (int j = 0; j < 4; ++j) {
            int d_l = dq * 4 + j;
            LH[d_l * 32 + (cp ^ (d_l & 31))] =
                (uint_t)f2h(aa[j]) | ((uint_t)f2h(bb[j]) << 16);
        }
    }
    __syncthreads();

    const int d_l = t >> 2;
    const int wq4 = (t & 3) * 8;
    uint_t vh[8];
    #pragma unroll
    for (int i = 0; i < 8; ++i)
        vh[i] = LH[d_l * 32 + ((wq4 + i) ^ (d_l & 31))];
    size_t base = (outRow0 + d_l) * 256 + c0 / 2 + wq4;
    *(uint4*)&oh[base]     = *(uint4*)&vh[0];
    *(uint4*)&oh[base + 4] = *(uint4*)&vh[4];
}

// ---------------------------------------------------------------------------
// Kernel 1: MFMA QKV projection — fp16 single-combo, single-buffer LDS with
// register prefetch (R5 pipeline, the proven best).
// Q,K outputs: fp16 planes [inst][n][64]. V: bf16 plane vt[inst][hd][n]
// (PV kv-permutation baked in), since PV runs in bf16.
// ---------------------------------------------------------------------------
__global__ __launch_bounds__(256) void proj_kernel(
    const _Float16* __restrict__ xt, const _Float16* __restrict__ wt,
    const float* __restrict__ bq, const float* __restrict__ bk,
    const float* __restrict__ bv,
    ushort_t* __restrict__ qf, ushort_t* __restrict__ kf,
    ushort_t* __restrict__ vt)
{
    __shared__ _Float16 POOL[16384];   // 32 KB (staging uses 16 KB; V-epi all)
    _Float16* As = POOL;               // [128 rows][4 groups x 8 halfs]
    _Float16* Bs = POOL + 4096;

    const int tok0  = blockIdx.x * 128;
    const int b     = tok0 >> 10;
    const int ntb   = tok0 & 1023;
    const int by    = blockIdx.y;
    const int which = by >> 2;                       // 0=q,1=k,2=v
    const int nloc0 = (by & 3) * 128;

    const int t   = threadIdx.x;
    const int w   = t >> 6;
    const int l   = t & 63;
    const int l31 = l & 31;
    const int h5  = l >> 5;
    const int wm  = w & 1;
    const int wn  = w >> 1;

    const int g   = t & 3;
    const int r0  = t >> 2;                          // 0..63, rep adds 64
    const int swz = g ^ (r0 & 3);

    const _Float16* baseA = xt + (size_t)(tok0 + r0) * 512 + g * 8;
    const _Float16* baseB = wt + (size_t)(which * 512 + nloc0 + r0) * 512 + g * 8;

    v8h pfa[2], pfb[2];
    auto load_tile = [&](int k0) {
        #pragma unroll
        for (int rep = 0; rep < 2; ++rep) {
            pfa[rep] = *(const v8h*)(baseA + rep * 32768 + k0);
            pfb[rep] = *(const v8h*)(baseB + rep * 32768 + k0);
        }
    };
    auto store_tile = [&]() {
        #pragma unroll
        for (int rep = 0; rep < 2; ++rep) {
            int so = ((rep * 64 + r0) * 4 + swz) * 8;
            *(v8h*)&As[so] = pfa[rep];
            *(v8h*)&Bs[so] = pfb[rep];
        }
    };

    v16f acc[2][2] = {{{}, {}}, {{}, {}}};

    load_tile(0);
    store_tile();
    __syncthreads();

    for (int step = 0; step < 16; ++step) {
        if (step < 15) load_tile((step + 1) * 32);

        #pragma unroll
        for (int kc = 0; kc < 2; ++kc) {
            v8h af[2], bf[2];
            #pragma unroll
            for (int ms = 0; ms < 2; ++ms) {
                int rm = wm * 64 + ms * 32 + l31;
                af[ms] = *(const v8h*)&As[(rm * 4 + ((kc * 2 + h5) ^ (rm & 3))) * 8];
            }
            #pragma unroll
            for (int ns = 0; ns < 2; ++ns) {
                int rn = wn * 64 + ns * 32 + l31;
                bf[ns] = *(const v8h*)&Bs[(rn * 4 + ((kc * 2 + h5) ^ (rn & 3))) * 8];
            }
            #pragma unroll
            for (int ms = 0; ms < 2; ++ms)
                #pragma unroll
                for (int ns = 0; ns < 2; ++ns)
                    acc[ms][ns] = __builtin_amdgcn_mfma_f32_32x32x16_f16(
                        af[ms], bf[ns], acc[ms][ns], 0, 0, 0);
        }

        __syncthreads();
        if (step < 15) {
            store_tile();                 // vmcnt wait lands here, post-compute
            __syncthreads();
        }
    }

    // ---- epilogue ----
    if (which < 2) {
        ushort_t* oh = (which == 0) ? qf : kf;
        const float* bias = (which == 0) ? bq : bk;
        #pragma unroll
        for (int ns = 0; ns < 2; ++ns) {
            int d_local = nloc0 + wn * 64 + ns * 32 + l31;
            float bvv  = bias[d_local];
            int head   = d_local >> 6;
            int hd     = d_local & 63;
            size_t pb  = (size_t)(b * HEADS_ + head) * 65536 + hd;
            #pragma unroll
            for (int ms = 0; ms < 2; ++ms)
                #pragma unroll
                for (int r = 0; r < 16; ++r) {
                    int n = ntb + wm * 64 + ms * 32 + (r & 3) + 8 * (r >> 2) + 4 * h5;
                    oh[pb + (size_t)n * 64] = f2h(acc[ms][ns][r] + bvv);
                }
        }
    } else {
        float bvv[2];
        #pragma unroll
        for (int ns = 0; ns < 2; ++ns)
            bvv[ns] = bv[nloc0 + wn * 64 + ns * 32 + l31];
        __syncthreads();                 // staging LDS fully consumed
        uint_t* TW = (uint_t*)POOL + w * 2048;   // wave-private 8 KB
        #pragma unroll
        for (int ms = 0; ms < 2; ++ms)
            #pragma unroll
            for (int ns = 0; ns < 2; ++ns)
                #pragma unroll
                for (int r = 0; r < 16; r += 2) {
                    int tok_l = ms * 32 + (r & 3) + 8 * (r >> 2) + 4 * h5;
                    int hd_l  = ns * 32 + l31;
                    TW[hd_l * 32 + ((tok_l >> 1) ^ (hd_l & 31))] =
                        pkbf(acc[ms][ns][r] + bvv[ns], acc[ms][ns][r + 1] + bvv[ns]);
                }
        __syncthreads();
        const int head = (nloc0 + wn * 64) >> 6;
        uint_t* vtu = (uint_t*)vt;
        size_t base = (size_t)(b * HEADS_ + head) * 32768 + (size_t)l * 512
                    + (ntb + wm * 64) / 2;
        #pragma unroll
        for (int c = 0; c < 8; ++c) {
            uint_t wd[4];
            #pragma unroll
            for (int kk = 0; kk < 4; ++kk) {
                int wsx = c * 4 + kk;
                int w3 = wsx & 7;
                int sw = (wsx & ~7) | (w3 & 1) | (((w3 >> 1) & 1) << 2)
                                   | (((w3 >> 2) & 1) << 1);
                wd[kk] = TW[l * 32 + (sw ^ (l & 31))];
            }
            *(uint4*)&vtu[base + c * 4] = *(uint4*)&wd[0];
        }
    }
}

// ---------------------------------------------------------------------------
// Kernel 2: MFMA flash attention, S^T form — fp16 QK^T (single combo),
// bf16 PV; single-buffer + register prefetch (R5 pipeline).
// ---------------------------------------------------------------------------
__global__ __launch_bounds__(256) void attn_kernel(
    const ushort_t* __restrict__ qf, const ushort_t* __restrict__ kf,
    const ushort_t* __restrict__ vt, float* __restrict__ out)
{
    __shared__ _Float16 KH[4096];      // K tile [kv][d] fp16, swizzled
    __shared__ ushort_t VT[4096];      // V^T tile [hd][kv-permuted] bf16
    __shared__ float    RS[128];

    const int inst  = blockIdx.x;
    const int chunk = blockIdx.y;
    const int t     = threadIdx.x;
    const int w     = t >> 6;
    const int l     = t & 63;
    const int l31   = l & 31;
    const int h5    = l >> 5;

    const ushort_t* Qf = qf + (size_t)inst * 65536;
    const ushort_t* Kf = kf + (size_t)inst * 65536;
    const ushort_t* Vt = vt + (size_t)inst * 65536;

    const int qbase = chunk * 128 + w * 32;

    v8h aq[4];
    #pragma unroll
    for (int ks = 0; ks < 4; ++ks)
        aq[ks] = *(const v8h*)&Qf[(size_t)(qbase + l31) * 64 + ks * 16 + h5 * 8];

    const int g   = t & 7;
    const int r0  = t >> 3;            // 0..31, rep adds 32
    const int swz = g ^ (r0 & 7);
    const ushort_t* baseK = Kf + (size_t)r0 * 64 + g * 8;
    const ushort_t* baseV = Vt + (size_t)r0 * 1024 + g * 8;

    v8h pk[2]; v8s pv[2];
    auto load_tile = [&](int kt) {
        #pragma unroll
        for (int rep = 0; rep < 2; ++rep) {
            pk[rep] = *(const v8h*)(baseK + (size_t)kt * 4096 + rep * 2048);
            pv[rep] = *(const v8s*)(baseV + (size_t)rep * 32768 + kt * 64);
        }
    };
    auto store_tile = [&]() {
        #pragma unroll
        for (int rep = 0; rep < 2; ++rep) {
            int so = ((rep * 32 + r0) * 8 + swz) * 8;
            *(v8h*)&KH[so] = pk[rep];
            *(v8s*)&VT[so] = pv[rep];
        }
    };

    v16f O0 = {}, O1 = {};
    float rsumv = 0.f;

    load_tile(0);
    store_tile();
    __syncthreads();

    for (int kt = 0; kt < 16; ++kt) {
        if (kt < 15) load_tile(kt + 1);

        #pragma unroll
        for (int t2 = 0; t2 < 2; ++t2) {
            v16f s = {};
            int kvrow = t2 * 32 + l31;
            #pragma unroll
            for (int ks = 0; ks < 4; ++ks) {
                int so = (kvrow * 8 + ((ks * 2 + h5) ^ (kvrow & 7))) * 8;
                v8h khf = *(const v8h*)&KH[so];
                s = __builtin_amdgcn_mfma_f32_32x32x16_f16(khf, aq[ks], s, 0, 0, 0);
            }
            float e0[8], e1[8];
            #pragma unroll
            for (int j = 0; j < 8; ++j) {
                e0[j] = __expf(s[j] - 64.0f);
                e1[j] = __expf(s[8 + j] - 64.0f);
                rsumv += e0[j] + e1[j];
            }
            uint4 u0, u1;
            u0.x = pkbf(e0[0], e0[1]); u0.y = pkbf(e0[2], e0[3]);
            u0.z = pkbf(e0[4], e0[5]); u0.w = pkbf(e0[6], e0[7]);
            u1.x = pkbf(e1[0], e1[1]); u1.y = pkbf(e1[2], e1[3]);
            u1.z = pkbf(e1[4], e1[5]); u1.w = pkbf(e1[6], e1[7]);
            v8s p0 = __builtin_bit_cast(v8s, u0);
            v8s p1 = __builtin_bit_cast(v8s, u1);

            #pragma unroll
            for (int hh = 0; hh < 2; ++hh) {
                int rv = hh * 32 + l31;
                int g0 = (4 * t2 + h5)     ^ (rv & 7);
                int g1 = (4 * t2 + 2 + h5) ^ (rv & 7);
                v8s bv0 = *(const v8s*)&VT[(rv * 8 + g0) * 8];
                v8s bv1 = *(const v8s*)&VT[(rv * 8 + g1) * 8];
                if (hh == 0) {
                    O0 = __builtin_amdgcn_mfma_f32_32x32x16_bf16(p0, bv0, O0, 0, 0, 0);
                    O0 = __builtin_amdgcn_mfma_f32_32x32x16_bf16(p1, bv1, O0, 0, 0, 0);
                } else {
                    O1 = __builtin_amdgcn_mfma_f32_32x32x16_bf16(p0, bv0, O1, 0, 0, 0);
                    O1 = __builtin_amdgcn_mfma_f32_32x32x16_bf16(p1, bv1, O1, 0, 0, 0);
                }
            }
        }

        __syncthreads();
        if (kt < 15) {
            store_tile();
            __syncthreads();
        }
    }

    float tot = rsumv + __shfl_xor(rsumv, 32, 64);
    if (h5 == 0) RS[w * 32 + l31] = 1.0f / tot;
    __syncthreads();
    float invr[16];
    #pragma unroll
    for (int r = 0; r < 16; ++r)
        invr[r] = RS[w * 32 + (r & 3) + 8 * (r >> 2) + 4 * h5];

    const int b    = inst >> 3;
    const int head = inst & 7;
    float* ob = out + (size_t)b * C_ * N_;
    #pragma unroll
    for (int hh = 0; hh < 2; ++hh) {
        const v16f& O = hh ? O1 : O0;
        int c = head * 64 + hh * 32 + l31;
        #pragma unroll
        for (int qd = 0; qd < 4; ++qd) {
            int n = qbase + 8 * qd + 4 * h5;
            float4 o4;
            o4.x = O[qd * 4 + 0] * invr[qd * 4 + 0];
            o4.y = O[qd * 4 + 1] * invr[qd * 4 + 1];
            o4.z = O[qd * 4 + 2] * invr[qd * 4 + 2];
            o4.w = O[qd * 4 + 3] * invr[qd * 4 + 3];
            *(float4*)&ob[(size_t)c * N_ + n] = o4;
        }
    }
}

// ---------------------------------------------------------------------------
extern "C" void kernel_launch(void* const* d_in, const int* in_sizes, int n_in,
                              void* d_out, int out_size, void* d_ws, size_t ws_size,
                              hipStream_t stream) {
    const float* x  = (const float*)d_in[0];
    const float* wq = (const float*)d_in[1];
    const float* bq = (const float*)d_in[2];
    const float* wk = (const float*)d_in[3];
    const float* bk = (const float*)d_in[4];
    const float* wv = (const float*)d_in[5];
    const float* bv = (const float*)d_in[6];
    float* out = (float*)d_out;

    char* ws = (char*)d_ws;                        // ~35 MiB used
    _Float16* wt = (_Float16*)(ws);                // 1536x512 fp16 = 1.5 MiB
    _Float16* xt = (_Float16*)(ws + 1572864);      // 8192x512 fp16 = 8 MiB
    ushort_t* qf = (ushort_t*)(ws + 9961472);      // 8 MiB fp16
    ushort_t* kf = (ushort_t*)(ws + 18350080);     // 8 MiB fp16
    ushort_t* vt = (ushort_t*)(ws + 26738688);     // 8 MiB bf16

    prep_kernel<<<dim3(16, 8, 11), 256, 0, stream>>>(
        x, wq, wk, wv, (uint_t*)wt, (uint_t*)xt);
    proj_kernel<<<dim3(64, 12), 256, 0, stream>>>(xt, wt, bq, bk, bv,
                                                  qf, kf, vt);
    attn_kernel<<<dim3(64, 8), 256, 0, stream>>>(qf, kf, vt, out);
}